// Round 1
// baseline (645.626 us; speedup 1.0000x reference)
//
#include <hip/hip_runtime.h>
#include <hip/hip_bf16.h>

#define Dd 1024
#define Hh 4096
#define Ee 8
#define Tt 4096   // tokens = 2*2048
#define Kk 2

typedef __attribute__((ext_vector_type(8))) short short8;
typedef __attribute__((ext_vector_type(4))) float f32x4;

__device__ __forceinline__ unsigned short f2bf_bits(float f) {
  unsigned u = __builtin_bit_cast(unsigned, f);
  u += 0x7FFFu + ((u >> 16) & 1u);   // RNE (finite values)
  return (unsigned short)(u >> 16);
}

__device__ __forceinline__ void glds16(const void* g, void* l) {
  __builtin_amdgcn_global_load_lds(
      (const __attribute__((address_space(1))) unsigned int*)g,
      (__attribute__((address_space(3))) unsigned int*)l, 16, 0, 0);
}

// ---------------- fp32 -> bf16 conversion (vectorized) ----------------
__global__ __launch_bounds__(256) void cvt_kernel(const float* __restrict__ src,
                                                  unsigned short* __restrict__ dst, int n4) {
  int i = blockIdx.x * blockDim.x + threadIdx.x;
  int stride = gridDim.x * blockDim.x;
  for (; i < n4; i += stride) {
    float4 v = reinterpret_cast<const float4*>(src)[i];
    ushort4 o;
    o.x = f2bf_bits(v.x);
    o.y = f2bf_bits(v.y);
    o.z = f2bf_bits(v.z);
    o.w = f2bf_bits(v.w);
    reinterpret_cast<ushort4*>(dst)[i] = o;
  }
}

// ---------------- router: softmax + top-2 + expert lists ----------------
__global__ __launch_bounds__(256) void router_kernel(
    const float* __restrict__ x, const float* __restrict__ Wr, const float* __restrict__ br,
    int* __restrict__ cnt, int* __restrict__ list, float* __restrict__ g2) {
  int t = blockIdx.x * 4 + (threadIdx.x >> 6);
  int lane = threadIdx.x & 63;
  const float* xr = x + (size_t)t * Dd;
  float pe[Ee];
#pragma unroll
  for (int e = 0; e < Ee; e++) pe[e] = 0.f;
  for (int d = lane; d < Dd; d += 64) {
    float xv = xr[d];
#pragma unroll
    for (int e = 0; e < Ee; e++) pe[e] += xv * Wr[e * Dd + d];
  }
#pragma unroll
  for (int e = 0; e < Ee; e++) {
    float v = pe[e];
#pragma unroll
    for (int s = 32; s > 0; s >>= 1) v += __shfl_xor(v, s);
    pe[e] = v + br[e];
  }
  if (lane == 0) {
    float mx = pe[0];
#pragma unroll
    for (int e = 1; e < Ee; e++) mx = fmaxf(mx, pe[e]);
    float g[Ee];
    float sum = 0.f;
#pragma unroll
    for (int e = 0; e < Ee; e++) { g[e] = expf(pe[e] - mx); sum += g[e]; }
    float inv = 1.0f / sum;
    int e0 = 0; float g0v = g[0];
#pragma unroll
    for (int e = 1; e < Ee; e++) if (g[e] > g0v) { g0v = g[e]; e0 = e; }
    int e1 = -1; float g1v = -1.f;
#pragma unroll
    for (int e = 0; e < Ee; e++) if (e != e0 && g[e] > g1v) { g1v = g[e]; e1 = e; }
    g2[t * 2 + 0] = g0v * inv;
    g2[t * 2 + 1] = g1v * inv;
    int p0 = atomicAdd(&cnt[e0], 1);
    list[e0 * Tt + p0] = t * 2;
    int p1 = atomicAdd(&cnt[e1], 1);
    list[e1 * Tt + p1] = t * 2 + 1;
  }
}

__global__ void scan_kernel(const int* __restrict__ cnt, int* __restrict__ offs) {
  if (threadIdx.x == 0 && blockIdx.x == 0) {
    int a = 0;
    for (int e = 0; e < Ee; e++) { offs[e] = a; a += cnt[e]; }
  }
}

// ---------------- GEMM1: h = gelu(x_gathered @ W1[e]^T + b1[e]) -> bf16 ----------------
// 128x128 tile, BK=32, 4 waves (2x2), 16x16x32 bf16 MFMA.
// LDS layout: [kb(4)][row(128)][8 bf16]  (linear for global_load_lds, ~conflict-free reads)
__global__ __launch_bounds__(256) void gemm1_kernel(
    const unsigned short* __restrict__ xb, const unsigned short* __restrict__ w1b,
    const float* __restrict__ b1,
    const int* __restrict__ cnt, const int* __restrict__ offs, const int* __restrict__ list,
    unsigned short* __restrict__ hb) {
  const int NT = Hh / 128;  // 32
  const int MT = Tt / 128;  // 32
  int bid = blockIdx.x;
  int e = bid / (MT * NT);
  int rem = bid % (MT * NT);
  int mt = rem / NT;
  int nt = rem % NT;
  int ce = cnt[e];
  if (mt * 128 >= ce) return;

  __shared__ short As[4096];
  __shared__ short Bs[4096];

  int tid = threadIdx.x;
  int lane = tid & 63;
  int w = tid >> 6;
  int wm = w >> 1, wn = w & 1;
  int fr = lane & 15, kq = lane >> 4;

  int li0 = tid;
  int li1 = 256 + tid;
  int rowA0 = li0 & 127, kb0 = li0 >> 7;
  int rowA1 = li1 & 127, kb1 = li1 >> 7;
  int gr0 = mt * 128 + rowA0;
  int gr1 = mt * 128 + rowA1;
  int t0 = (gr0 < ce) ? (list[e * Tt + gr0] >> 1) : 0;
  int t1 = (gr1 < ce) ? (list[e * Tt + gr1] >> 1) : 0;
  const unsigned short* a0 = xb + (size_t)t0 * Dd + kb0 * 8;
  const unsigned short* a1 = xb + (size_t)t1 * Dd + kb1 * 8;
  const unsigned short* bbase = w1b + (size_t)e * Hh * Dd + (size_t)(nt * 128) * Dd;
  const unsigned short* b0 = bbase + (size_t)rowA0 * Dd + kb0 * 8;
  const unsigned short* b1q = bbase + (size_t)rowA1 * Dd + kb1 * 8;
  short* Ad0 = &As[(w * 64) * 8];
  short* Ad1 = &As[(256 + w * 64) * 8];
  short* Bd0 = &Bs[(w * 64) * 8];
  short* Bd1 = &Bs[(256 + w * 64) * 8];

  f32x4 acc[4][4] = {};

  for (int k0 = 0; k0 < Dd; k0 += 32) {
    glds16(a0 + k0, Ad0);
    glds16(a1 + k0, Ad1);
    glds16(b0 + k0, Bd0);
    glds16(b1q + k0, Bd1);
    __syncthreads();
    short8 af[4], bfr[4];
#pragma unroll
    for (int i = 0; i < 4; i++)
      af[i] = *reinterpret_cast<const short8*>(&As[kq * 1024 + (wm * 64 + i * 16 + fr) * 8]);
#pragma unroll
    for (int j = 0; j < 4; j++)
      bfr[j] = *reinterpret_cast<const short8*>(&Bs[kq * 1024 + (wn * 64 + j * 16 + fr) * 8]);
#pragma unroll
    for (int i = 0; i < 4; i++)
#pragma unroll
      for (int j = 0; j < 4; j++)
        acc[i][j] = __builtin_amdgcn_mfma_f32_16x16x32_bf16(af[i], bfr[j], acc[i][j], 0, 0, 0);
    __syncthreads();
  }

  int off_e = offs[e];
  const float* b1e = b1 + (size_t)e * Hh;
#pragma unroll
  for (int i = 0; i < 4; i++) {
    int rb = wm * 64 + i * 16 + kq * 4;
#pragma unroll
    for (int j = 0; j < 4; j++) {
      int col = nt * 128 + wn * 64 + j * 16 + fr;
      float bias = b1e[col];
#pragma unroll
      for (int rr = 0; rr < 4; rr++) {
        int grow = mt * 128 + rb + rr;
        if (grow < ce) {
          float v = acc[i][j][rr] + bias;
          v = 0.5f * v * (1.0f + erff(v * 0.70710678118654752f));
          hb[(size_t)(off_e + grow) * Hh + col] = f2bf_bits(v);
        }
      }
    }
  }
}

// ---------------- GEMM2: y = h @ W2[e]^T + b2[e] -> fp32 scattered to (t,k) ----------------
__global__ __launch_bounds__(256) void gemm2_kernel(
    const unsigned short* __restrict__ hb, const unsigned short* __restrict__ w2b,
    const float* __restrict__ b2,
    const int* __restrict__ cnt, const int* __restrict__ offs, const int* __restrict__ list,
    float* __restrict__ y) {
  const int NT = Dd / 128;  // 8
  const int MT = Tt / 128;  // 32
  int bid = blockIdx.x;
  int e = bid / (MT * NT);
  int rem = bid % (MT * NT);
  int mt = rem / NT;
  int nt = rem % NT;
  int ce = cnt[e];
  if (mt * 128 >= ce) return;

  __shared__ short As[4096];
  __shared__ short Bs[4096];
  __shared__ int ents[128];

  int tid = threadIdx.x;
  if (tid < 128) {
    int grow = mt * 128 + tid;
    ents[tid] = (grow < ce) ? list[e * Tt + grow] : -1;
  }

  int lane = tid & 63;
  int w = tid >> 6;
  int wm = w >> 1, wn = w & 1;
  int fr = lane & 15, kq = lane >> 4;

  int li0 = tid;
  int li1 = 256 + tid;
  int rowA0 = li0 & 127, kb0 = li0 >> 7;
  int rowA1 = li1 & 127, kb1 = li1 >> 7;
  int off_e = offs[e];
  int gA0 = mt * 128 + rowA0; if (gA0 >= ce) gA0 = ce - 1;
  int gA1 = mt * 128 + rowA1; if (gA1 >= ce) gA1 = ce - 1;
  const unsigned short* a0 = hb + (size_t)(off_e + gA0) * Hh + kb0 * 8;
  const unsigned short* a1 = hb + (size_t)(off_e + gA1) * Hh + kb1 * 8;
  const unsigned short* bbase = w2b + (size_t)e * Dd * Hh + (size_t)(nt * 128) * Hh;
  const unsigned short* b0 = bbase + (size_t)rowA0 * Hh + kb0 * 8;
  const unsigned short* b1q = bbase + (size_t)rowA1 * Hh + kb1 * 8;
  short* Ad0 = &As[(w * 64) * 8];
  short* Ad1 = &As[(256 + w * 64) * 8];
  short* Bd0 = &Bs[(w * 64) * 8];
  short* Bd1 = &Bs[(256 + w * 64) * 8];

  f32x4 acc[4][4] = {};

  for (int k0 = 0; k0 < Hh; k0 += 32) {
    glds16(a0 + k0, Ad0);
    glds16(a1 + k0, Ad1);
    glds16(b0 + k0, Bd0);
    glds16(b1q + k0, Bd1);
    __syncthreads();
    short8 af[4], bfr[4];
#pragma unroll
    for (int i = 0; i < 4; i++)
      af[i] = *reinterpret_cast<const short8*>(&As[kq * 1024 + (wm * 64 + i * 16 + fr) * 8]);
#pragma unroll
    for (int j = 0; j < 4; j++)
      bfr[j] = *reinterpret_cast<const short8*>(&Bs[kq * 1024 + (wn * 64 + j * 16 + fr) * 8]);
#pragma unroll
    for (int i = 0; i < 4; i++)
#pragma unroll
      for (int j = 0; j < 4; j++)
        acc[i][j] = __builtin_amdgcn_mfma_f32_16x16x32_bf16(af[i], bfr[j], acc[i][j], 0, 0, 0);
    __syncthreads();
  }

  const float* b2e = b2 + (size_t)e * Dd;
#pragma unroll
  for (int i = 0; i < 4; i++) {
    int rb = wm * 64 + i * 16 + kq * 4;
#pragma unroll
    for (int j = 0; j < 4; j++) {
      int col = nt * 128 + wn * 64 + j * 16 + fr;
      float bias = b2e[col];
#pragma unroll
      for (int rr = 0; rr < 4; rr++) {
        int en = ents[rb + rr];
        if (en >= 0) y[(size_t)en * Dd + col] = acc[i][j][rr] + bias;
      }
    }
  }
}

// ---------------- combine: out[t] = g0*y[2t] + g1*y[2t+1] ----------------
__global__ __launch_bounds__(256) void combine_kernel(
    const float* __restrict__ y, const float* __restrict__ g2, float* __restrict__ out) {
  const int C4 = Dd / 4;  // 256
  int i = blockIdx.x * blockDim.x + threadIdx.x;  // over Tt*Dd/4
  int t = i / C4;
  int c = i % C4;
  float g0 = g2[t * 2 + 0];
  float g1 = g2[t * 2 + 1];
  float4 y0 = reinterpret_cast<const float4*>(y)[(size_t)(t * 2 + 0) * C4 + c];
  float4 y1 = reinterpret_cast<const float4*>(y)[(size_t)(t * 2 + 1) * C4 + c];
  float4 o;
  o.x = g0 * y0.x + g1 * y1.x;
  o.y = g0 * y0.y + g1 * y1.y;
  o.z = g0 * y0.z + g1 * y1.z;
  o.w = g0 * y0.w + g1 * y1.w;
  reinterpret_cast<float4*>(out)[i] = o;
}

extern "C" void kernel_launch(void* const* d_in, const int* in_sizes, int n_in,
                              void* d_out, int out_size, void* d_ws, size_t ws_size,
                              hipStream_t stream) {
  const float* x  = (const float*)d_in[0];
  const float* Wr = (const float*)d_in[1];
  const float* br = (const float*)d_in[2];
  const float* W1 = (const float*)d_in[3];
  const float* b1 = (const float*)d_in[4];
  const float* W2 = (const float*)d_in[5];
  const float* b2 = (const float*)d_in[6];
  float* out = (float*)d_out;

  char* base = (char*)d_ws;
  size_t o = 0;
  auto alloc = [&](size_t n) { char* r = base + o; o += (n + 255) & ~(size_t)255; return r; };
  unsigned short* w1b = (unsigned short*)alloc((size_t)Ee * Hh * Dd * 2);
  unsigned short* w2b = (unsigned short*)alloc((size_t)Ee * Dd * Hh * 2);
  unsigned short* xb  = (unsigned short*)alloc((size_t)Tt * Dd * 2);
  unsigned short* hb  = (unsigned short*)alloc((size_t)Tt * Kk * Hh * 2);
  float* y   = (float*)alloc((size_t)Tt * Kk * Dd * 4);
  int* list  = (int*)alloc((size_t)Ee * Tt * 4);
  float* g2  = (float*)alloc((size_t)Tt * Kk * 4);
  int* cnt   = (int*)alloc(Ee * 4);
  int* offs  = (int*)alloc(Ee * 4);
  if (o > ws_size) return;  // workspace too small: fail loudly (output stays poisoned)

  hipMemsetAsync(cnt, 0, Ee * 4, stream);

  cvt_kernel<<<1024, 256, 0, stream>>>(x, xb, Tt * Dd / 4);
  cvt_kernel<<<4096, 256, 0, stream>>>(W1, w1b, Ee * Hh * Dd / 4);
  cvt_kernel<<<4096, 256, 0, stream>>>(W2, w2b, Ee * Dd * Hh / 4);

  router_kernel<<<Tt / 4, 256, 0, stream>>>(x, Wr, br, cnt, list, g2);
  scan_kernel<<<1, 64, 0, stream>>>(cnt, offs);

  gemm1_kernel<<<Ee * (Tt / 128) * (Hh / 128), 256, 0, stream>>>(xb, w1b, b1, cnt, offs, list, hb);
  gemm2_kernel<<<Ee * (Tt / 128) * (Dd / 128), 256, 0, stream>>>(hb, w2b, b2, cnt, offs, list, y);

  combine_kernel<<<(Tt * Dd / 4) / 256, 256, 0, stream>>>(y, g2, out);
}

// Round 2
// 642.519 us; speedup vs baseline: 1.0048x; 1.0048x over previous
//
#include <hip/hip_runtime.h>
#include <hip/hip_bf16.h>

#define Dd 1024
#define Hh 4096
#define Ee 8
#define Tt 4096   // tokens = 2*2048
#define Kk 2

typedef __attribute__((ext_vector_type(8))) short short8;
typedef __attribute__((ext_vector_type(4))) float f32x4;

__device__ __forceinline__ unsigned short f2bf_bits(float f) {
  unsigned u = __builtin_bit_cast(unsigned, f);
  u += 0x7FFFu + ((u >> 16) & 1u);   // RNE (finite values)
  return (unsigned short)(u >> 16);
}

__device__ __forceinline__ void glds16(const void* g, void* l) {
  __builtin_amdgcn_global_load_lds(
      (const __attribute__((address_space(1))) unsigned int*)g,
      (__attribute__((address_space(3))) unsigned int*)l, 16, 0, 0);
}

// ---------------- fp32 -> bf16 conversion (vectorized) ----------------
__global__ __launch_bounds__(256) void cvt_kernel(const float* __restrict__ src,
                                                  unsigned short* __restrict__ dst, int n4) {
  int i = blockIdx.x * blockDim.x + threadIdx.x;
  int stride = gridDim.x * blockDim.x;
  for (; i < n4; i += stride) {
    float4 v = reinterpret_cast<const float4*>(src)[i];
    ushort4 o;
    o.x = f2bf_bits(v.x);
    o.y = f2bf_bits(v.y);
    o.z = f2bf_bits(v.z);
    o.w = f2bf_bits(v.w);
    reinterpret_cast<ushort4*>(dst)[i] = o;
  }
}

// ---------------- router: softmax + top-2 + expert lists ----------------
__global__ __launch_bounds__(256) void router_kernel(
    const float* __restrict__ x, const float* __restrict__ Wr, const float* __restrict__ br,
    int* __restrict__ cnt, int* __restrict__ list, float* __restrict__ g2) {
  int t = blockIdx.x * 4 + (threadIdx.x >> 6);
  int lane = threadIdx.x & 63;
  const float* xr = x + (size_t)t * Dd;
  float pe[Ee];
#pragma unroll
  for (int e = 0; e < Ee; e++) pe[e] = 0.f;
  for (int d = lane; d < Dd; d += 64) {
    float xv = xr[d];
#pragma unroll
    for (int e = 0; e < Ee; e++) pe[e] += xv * Wr[e * Dd + d];
  }
#pragma unroll
  for (int e = 0; e < Ee; e++) {
    float v = pe[e];
#pragma unroll
    for (int s = 32; s > 0; s >>= 1) v += __shfl_xor(v, s);
    pe[e] = v + br[e];
  }
  if (lane == 0) {
    float mx = pe[0];
#pragma unroll
    for (int e = 1; e < Ee; e++) mx = fmaxf(mx, pe[e]);
    float g[Ee];
    float sum = 0.f;
#pragma unroll
    for (int e = 0; e < Ee; e++) { g[e] = expf(pe[e] - mx); sum += g[e]; }
    float inv = 1.0f / sum;
    int e0 = 0; float g0v = g[0];
#pragma unroll
    for (int e = 1; e < Ee; e++) if (g[e] > g0v) { g0v = g[e]; e0 = e; }
    int e1 = -1; float g1v = -1.f;
#pragma unroll
    for (int e = 0; e < Ee; e++) if (e != e0 && g[e] > g1v) { g1v = g[e]; e1 = e; }
    g2[t * 2 + 0] = g0v * inv;
    g2[t * 2 + 1] = g1v * inv;
    int p0 = atomicAdd(&cnt[e0], 1);
    list[e0 * Tt + p0] = t * 2;
    int p1 = atomicAdd(&cnt[e1], 1);
    list[e1 * Tt + p1] = t * 2 + 1;
  }
}

__global__ void scan_kernel(const int* __restrict__ cnt, int* __restrict__ offs) {
  if (threadIdx.x == 0 && blockIdx.x == 0) {
    int a = 0;
    for (int e = 0; e < Ee; e++) { offs[e] = a; a += cnt[e]; }
  }
}

// ---------------- GEMM1: h = gelu(x_gathered @ W1[e]^T + b1[e]) -> bf16 ----------------
// 128x128 tile, BK=32, 4 waves (2x2), 16x16x32 bf16 MFMA.
// 2-phase double-buffered pipeline (T3-minimum): prefetch next K-tile via
// global_load_lds while computing current; raw s_barrier + vmcnt(0) once per step.
// Block swizzle: e = bid&7 (expert per XCD), mt-inner so co-resident blocks share B.
__global__ __launch_bounds__(256) void gemm1_kernel(
    const unsigned short* __restrict__ xb, const unsigned short* __restrict__ w1b,
    const float* __restrict__ b1,
    const int* __restrict__ cnt, const int* __restrict__ offs, const int* __restrict__ list,
    unsigned short* __restrict__ hb) {
  int bid = blockIdx.x;
  int e = bid & 7;
  int slot = bid >> 3;          // 0..1023
  int nt = slot >> 5;           // 0..31  (Hh/128)
  int mt = slot & 31;           // 0..31  (Tt/128), mt-inner
  int ce = cnt[e];
  if (mt * 128 >= ce) return;

  __shared__ short As[2][4096];
  __shared__ short Bs[2][4096];

  int tid = threadIdx.x;
  int lane = tid & 63;
  int w = tid >> 6;
  int wm = w >> 1, wn = w & 1;
  int fr = lane & 15, kq = lane >> 4;

  int rowA0 = tid & 127, kb0 = tid >> 7;   // threads cover [kb0(0,1)][row 0..127]
  int gr0 = mt * 128 + rowA0;
  int t0 = (gr0 < ce) ? (list[e * Tt + gr0] >> 1) : 0;
  const unsigned short* a0 = xb + (size_t)t0 * Dd + kb0 * 8;     // second half: +16 (kb+2)
  const unsigned short* b0 = w1b + (size_t)e * Hh * Dd + (size_t)(nt * 128 + rowA0) * Dd + kb0 * 8;

  short* AdA = &As[0][w * 512];
  short* AdB = &As[0][2048 + w * 512];
  short* BdA = &Bs[0][w * 512];
  short* BdB = &Bs[0][2048 + w * 512];

  int abase = kq * 1024 + (wm * 64 + fr) * 8;
  int bbase = kq * 1024 + (wn * 64 + fr) * 8;

  f32x4 acc[4][4] = {};

#define STAGE1(nb, k0)                         \
  do {                                         \
    int so_ = (nb)*4096;                       \
    glds16(a0 + (k0),      AdA + so_);         \
    glds16(a0 + (k0) + 16, AdB + so_);         \
    glds16(b0 + (k0),      BdA + so_);         \
    glds16(b0 + (k0) + 16, BdB + so_);         \
  } while (0)

#define COMPUTE1(nb)                                                        \
  do {                                                                      \
    const short* Ab_ = &As[(nb)][0];                                        \
    const short* Bb_ = &Bs[(nb)][0];                                        \
    short8 af[4], bv[4];                                                    \
    _Pragma("unroll") for (int i = 0; i < 4; i++)                           \
        af[i] = *reinterpret_cast<const short8*>(&Ab_[abase + i * 128]);    \
    _Pragma("unroll") for (int j = 0; j < 4; j++)                           \
        bv[j] = *reinterpret_cast<const short8*>(&Bb_[bbase + j * 128]);    \
    _Pragma("unroll") for (int i = 0; i < 4; i++)                           \
      _Pragma("unroll") for (int j = 0; j < 4; j++)                         \
          acc[i][j] = __builtin_amdgcn_mfma_f32_16x16x32_bf16(af[i], bv[j], \
                                                              acc[i][j], 0, 0, 0); \
  } while (0)

  STAGE1(0, 0);
  asm volatile("s_waitcnt vmcnt(0)" ::: "memory");
  __builtin_amdgcn_s_barrier();
  const int nkt = Dd / 32;  // 32
#pragma unroll 2
  for (int kt = 0; kt < nkt - 1; ++kt) {
    int cb = kt & 1;
    STAGE1(cb ^ 1, (kt + 1) * 32);
    COMPUTE1(cb);
    asm volatile("s_waitcnt vmcnt(0)" ::: "memory");
    __builtin_amdgcn_s_barrier();
  }
  COMPUTE1((nkt - 1) & 1);

  int off_e = offs[e];
  const float* b1e = b1 + (size_t)e * Hh;
#pragma unroll
  for (int i = 0; i < 4; i++) {
    int rb = wm * 64 + i * 16 + kq * 4;
#pragma unroll
    for (int j = 0; j < 4; j++) {
      int col = nt * 128 + wn * 64 + j * 16 + fr;
      float bias = b1e[col];
#pragma unroll
      for (int rr = 0; rr < 4; rr++) {
        int grow = mt * 128 + rb + rr;
        if (grow < ce) {
          float v = acc[i][j][rr] + bias;
          v = 0.5f * v * (1.0f + erff(v * 0.70710678118654752f));
          hb[(size_t)(off_e + grow) * Hh + col] = f2bf_bits(v);
        }
      }
    }
  }
#undef STAGE1
#undef COMPUTE1
}

// ---------------- GEMM2: y = h @ W2[e]^T + b2[e] -> fp32 scattered to (t,k) ----------------
__global__ __launch_bounds__(256) void gemm2_kernel(
    const unsigned short* __restrict__ hb, const unsigned short* __restrict__ w2b,
    const float* __restrict__ b2,
    const int* __restrict__ cnt, const int* __restrict__ offs, const int* __restrict__ list,
    float* __restrict__ y) {
  int bid = blockIdx.x;
  int e = bid & 7;
  int slot = bid >> 3;          // 0..255
  int nt = slot >> 5;           // 0..7   (Dd/128)
  int mt = slot & 31;           // 0..31  (Tt/128), mt-inner
  int ce = cnt[e];
  if (mt * 128 >= ce) return;

  __shared__ short As[2][4096];
  __shared__ short Bs[2][4096];
  __shared__ int ents[128];

  int tid = threadIdx.x;
  if (tid < 128) {
    int grow = mt * 128 + tid;
    ents[tid] = (grow < ce) ? list[e * Tt + grow] : -1;
  }

  int lane = tid & 63;
  int w = tid >> 6;
  int wm = w >> 1, wn = w & 1;
  int fr = lane & 15, kq = lane >> 4;

  int rowA0 = tid & 127, kb0 = tid >> 7;
  int off_e = offs[e];
  int gA0 = mt * 128 + rowA0; if (gA0 >= ce) gA0 = ce - 1;
  const unsigned short* a0 = hb + (size_t)(off_e + gA0) * Hh + kb0 * 8;
  const unsigned short* b0 = w2b + (size_t)e * Dd * Hh + (size_t)(nt * 128 + rowA0) * Hh + kb0 * 8;

  short* AdA = &As[0][w * 512];
  short* AdB = &As[0][2048 + w * 512];
  short* BdA = &Bs[0][w * 512];
  short* BdB = &Bs[0][2048 + w * 512];

  int abase = kq * 1024 + (wm * 64 + fr) * 8;
  int bbase = kq * 1024 + (wn * 64 + fr) * 8;

  f32x4 acc[4][4] = {};

#define STAGE2(nb, k0)                         \
  do {                                         \
    int so_ = (nb)*4096;                       \
    glds16(a0 + (k0),      AdA + so_);         \
    glds16(a0 + (k0) + 16, AdB + so_);         \
    glds16(b0 + (k0),      BdA + so_);         \
    glds16(b0 + (k0) + 16, BdB + so_);         \
  } while (0)

#define COMPUTE2(nb)                                                        \
  do {                                                                      \
    const short* Ab_ = &As[(nb)][0];                                        \
    const short* Bb_ = &Bs[(nb)][0];                                        \
    short8 af[4], bv[4];                                                    \
    _Pragma("unroll") for (int i = 0; i < 4; i++)                           \
        af[i] = *reinterpret_cast<const short8*>(&Ab_[abase + i * 128]);    \
    _Pragma("unroll") for (int j = 0; j < 4; j++)                           \
        bv[j] = *reinterpret_cast<const short8*>(&Bb_[bbase + j * 128]);    \
    _Pragma("unroll") for (int i = 0; i < 4; i++)                           \
      _Pragma("unroll") for (int j = 0; j < 4; j++)                         \
          acc[i][j] = __builtin_amdgcn_mfma_f32_16x16x32_bf16(af[i], bv[j], \
                                                              acc[i][j], 0, 0, 0); \
  } while (0)

  STAGE2(0, 0);
  asm volatile("s_waitcnt vmcnt(0)" ::: "memory");
  __builtin_amdgcn_s_barrier();
  const int nkt = Hh / 32;  // 128
#pragma unroll 2
  for (int kt = 0; kt < nkt - 1; ++kt) {
    int cb = kt & 1;
    STAGE2(cb ^ 1, (kt + 1) * 32);
    COMPUTE2(cb);
    asm volatile("s_waitcnt vmcnt(0)" ::: "memory");
    __builtin_amdgcn_s_barrier();
  }
  COMPUTE2((nkt - 1) & 1);

  const float* b2e = b2 + (size_t)e * Dd;
#pragma unroll
  for (int i = 0; i < 4; i++) {
    int rb = wm * 64 + i * 16 + kq * 4;
#pragma unroll
    for (int j = 0; j < 4; j++) {
      int col = nt * 128 + wn * 64 + j * 16 + fr;
      float bias = b2e[col];
#pragma unroll
      for (int rr = 0; rr < 4; rr++) {
        int en = ents[rb + rr];
        if (en >= 0) y[(size_t)en * Dd + col] = acc[i][j][rr] + bias;
      }
    }
  }
#undef STAGE2
#undef COMPUTE2
}

// ---------------- combine: out[t] = g0*y[2t] + g1*y[2t+1] ----------------
__global__ __launch_bounds__(256) void combine_kernel(
    const float* __restrict__ y, const float* __restrict__ g2, float* __restrict__ out) {
  const int C4 = Dd / 4;  // 256
  int i = blockIdx.x * blockDim.x + threadIdx.x;  // over Tt*Dd/4
  int t = i / C4;
  int c = i % C4;
  float g0 = g2[t * 2 + 0];
  float g1 = g2[t * 2 + 1];
  float4 y0 = reinterpret_cast<const float4*>(y)[(size_t)(t * 2 + 0) * C4 + c];
  float4 y1 = reinterpret_cast<const float4*>(y)[(size_t)(t * 2 + 1) * C4 + c];
  float4 o;
  o.x = g0 * y0.x + g1 * y1.x;
  o.y = g0 * y0.y + g1 * y1.y;
  o.z = g0 * y0.z + g1 * y1.z;
  o.w = g0 * y0.w + g1 * y1.w;
  reinterpret_cast<float4*>(out)[i] = o;
}

extern "C" void kernel_launch(void* const* d_in, const int* in_sizes, int n_in,
                              void* d_out, int out_size, void* d_ws, size_t ws_size,
                              hipStream_t stream) {
  const float* x  = (const float*)d_in[0];
  const float* Wr = (const float*)d_in[1];
  const float* br = (const float*)d_in[2];
  const float* W1 = (const float*)d_in[3];
  const float* b1 = (const float*)d_in[4];
  const float* W2 = (const float*)d_in[5];
  const float* b2 = (const float*)d_in[6];
  float* out = (float*)d_out;

  char* base = (char*)d_ws;
  size_t o = 0;
  auto alloc = [&](size_t n) { char* r = base + o; o += (n + 255) & ~(size_t)255; return r; };
  unsigned short* w1b = (unsigned short*)alloc((size_t)Ee * Hh * Dd * 2);
  unsigned short* w2b = (unsigned short*)alloc((size_t)Ee * Dd * Hh * 2);
  unsigned short* xb  = (unsigned short*)alloc((size_t)Tt * Dd * 2);
  unsigned short* hb  = (unsigned short*)alloc((size_t)Tt * Kk * Hh * 2);
  float* y   = (float*)alloc((size_t)Tt * Kk * Dd * 4);
  int* list  = (int*)alloc((size_t)Ee * Tt * 4);
  float* g2  = (float*)alloc((size_t)Tt * Kk * 4);
  int* cnt   = (int*)alloc(Ee * 4);
  int* offs  = (int*)alloc(Ee * 4);
  if (o > ws_size) return;  // workspace too small: fail loudly (output stays poisoned)

  hipMemsetAsync(cnt, 0, Ee * 4, stream);

  cvt_kernel<<<1024, 256, 0, stream>>>(x, xb, Tt * Dd / 4);
  cvt_kernel<<<4096, 256, 0, stream>>>(W1, w1b, Ee * Hh * Dd / 4);
  cvt_kernel<<<4096, 256, 0, stream>>>(W2, w2b, Ee * Dd * Hh / 4);

  router_kernel<<<Tt / 4, 256, 0, stream>>>(x, Wr, br, cnt, list, g2);
  scan_kernel<<<1, 64, 0, stream>>>(cnt, offs);

  gemm1_kernel<<<Ee * (Tt / 128) * (Hh / 128), 256, 0, stream>>>(xb, w1b, b1, cnt, offs, list, hb);
  gemm2_kernel<<<Ee * (Tt / 128) * (Dd / 128), 256, 0, stream>>>(hb, w2b, b2, cnt, offs, list, y);

  combine_kernel<<<(Tt * Dd / 4) / 256, 256, 0, stream>>>(y, g2, out);
}

// Round 3
// 624.874 us; speedup vs baseline: 1.0332x; 1.0282x over previous
//
#include <hip/hip_runtime.h>
#include <hip/hip_bf16.h>

#define Dd 1024
#define Hh 4096
#define Ee 8
#define Tt 4096   // tokens = 2*2048
#define Kk 2

typedef __attribute__((ext_vector_type(8))) short short8;
typedef __attribute__((ext_vector_type(4))) float f32x4;

__device__ __forceinline__ unsigned short f2bf_bits(float f) {
  unsigned u = __builtin_bit_cast(unsigned, f);
  u += 0x7FFFu + ((u >> 16) & 1u);   // RNE (finite values)
  return (unsigned short)(u >> 16);
}

__device__ __forceinline__ void glds16(const void* g, void* l) {
  __builtin_amdgcn_global_load_lds(
      (const __attribute__((address_space(1))) unsigned int*)g,
      (__attribute__((address_space(3))) unsigned int*)l, 16, 0, 0);
}

// ---------------- fp32 -> bf16 conversion (vectorized) ----------------
__global__ __launch_bounds__(256) void cvt_kernel(const float* __restrict__ src,
                                                  unsigned short* __restrict__ dst, int n4) {
  int i = blockIdx.x * blockDim.x + threadIdx.x;
  int stride = gridDim.x * blockDim.x;
  for (; i < n4; i += stride) {
    float4 v = reinterpret_cast<const float4*>(src)[i];
    ushort4 o;
    o.x = f2bf_bits(v.x);
    o.y = f2bf_bits(v.y);
    o.z = f2bf_bits(v.z);
    o.w = f2bf_bits(v.w);
    reinterpret_cast<ushort4*>(dst)[i] = o;
  }
}

// ---------------- router: softmax + top-2 + expert lists ----------------
__global__ __launch_bounds__(256) void router_kernel(
    const float* __restrict__ x, const float* __restrict__ Wr, const float* __restrict__ br,
    int* __restrict__ cnt, int* __restrict__ list, float* __restrict__ g2) {
  int t = blockIdx.x * 4 + (threadIdx.x >> 6);
  int lane = threadIdx.x & 63;
  const float* xr = x + (size_t)t * Dd;
  float pe[Ee];
#pragma unroll
  for (int e = 0; e < Ee; e++) pe[e] = 0.f;
  for (int d = lane; d < Dd; d += 64) {
    float xv = xr[d];
#pragma unroll
    for (int e = 0; e < Ee; e++) pe[e] += xv * Wr[e * Dd + d];
  }
#pragma unroll
  for (int e = 0; e < Ee; e++) {
    float v = pe[e];
#pragma unroll
    for (int s = 32; s > 0; s >>= 1) v += __shfl_xor(v, s);
    pe[e] = v + br[e];
  }
  if (lane == 0) {
    float mx = pe[0];
#pragma unroll
    for (int e = 1; e < Ee; e++) mx = fmaxf(mx, pe[e]);
    float g[Ee];
    float sum = 0.f;
#pragma unroll
    for (int e = 0; e < Ee; e++) { g[e] = expf(pe[e] - mx); sum += g[e]; }
    float inv = 1.0f / sum;
    int e0 = 0; float g0v = g[0];
#pragma unroll
    for (int e = 1; e < Ee; e++) if (g[e] > g0v) { g0v = g[e]; e0 = e; }
    int e1 = -1; float g1v = -1.f;
#pragma unroll
    for (int e = 0; e < Ee; e++) if (e != e0 && g[e] > g1v) { g1v = g[e]; e1 = e; }
    g2[t * 2 + 0] = g0v * inv;
    g2[t * 2 + 1] = g1v * inv;
    int p0 = atomicAdd(&cnt[e0], 1);
    list[e0 * Tt + p0] = t * 2;
    int p1 = atomicAdd(&cnt[e1], 1);
    list[e1 * Tt + p1] = t * 2 + 1;
  }
}

__global__ void scan_kernel(const int* __restrict__ cnt, int* __restrict__ offs) {
  if (threadIdx.x == 0 && blockIdx.x == 0) {
    int a = 0;
    for (int e = 0; e < Ee; e++) { offs[e] = a; a += cnt[e]; }
  }
}

// Shared pipeline macros: 3-deep LDS double... triple-buffer, counted vmcnt (T3+T4).
// Per wave per STAGE: exactly 4 glds (VMEM). In-loop: vmcnt(8) keeps 2 tiles in flight.
#define STAGE(so_, k0)                          \
  do {                                          \
    glds16(a0 + (k0),      AdA + (so_));        \
    glds16(a0 + (k0) + 16, AdB + (so_));        \
    glds16(b0 + (k0),      BdA + (so_));        \
    glds16(b0 + (k0) + 16, BdB + (so_));        \
  } while (0)

#define COMPUTE(so_)                                                          \
  do {                                                                        \
    const short* Ab_ = &As[(so_)];                                            \
    const short* Bb_ = &Bs[(so_)];                                            \
    short8 af[4], bv[4];                                                      \
    _Pragma("unroll") for (int i = 0; i < 4; i++)                             \
        af[i] = *reinterpret_cast<const short8*>(&Ab_[abase + i * 128]);      \
    _Pragma("unroll") for (int j = 0; j < 4; j++)                             \
        bv[j] = *reinterpret_cast<const short8*>(&Bb_[bbase + j * 128]);      \
    _Pragma("unroll") for (int i = 0; i < 4; i++)                             \
      _Pragma("unroll") for (int j = 0; j < 4; j++)                           \
          acc[i][j] = __builtin_amdgcn_mfma_f32_16x16x32_bf16(af[i], bv[j],   \
                                                              acc[i][j], 0, 0, 0); \
  } while (0)

#define ROT(c_) ((c_) == 2 ? 0 : (c_) + 1)

// ---------------- GEMM1: h = gelu(x_gathered @ W1[e]^T + b1[e]) -> bf16 ----------------
// 128x128 tile, BK=32, 4 waves (2x2), 16x16x32 bf16 MFMA. 3-buffer counted-vmcnt pipeline.
__global__ __launch_bounds__(256) void gemm1_kernel(
    const unsigned short* __restrict__ xb, const unsigned short* __restrict__ w1b,
    const float* __restrict__ b1,
    const int* __restrict__ cnt, const int* __restrict__ offs, const int* __restrict__ list,
    unsigned short* __restrict__ hb) {
  int bid = blockIdx.x;
  int e = bid & 7;
  int slot = bid >> 3;          // 0..1023
  int nt = slot >> 5;           // 0..31  (Hh/128)
  int mt = slot & 31;           // 0..31  (Tt/128), mt-inner
  int ce = cnt[e];
  if (mt * 128 >= ce) return;

  __shared__ short As[3 * 4096];
  __shared__ short Bs[3 * 4096];

  int tid = threadIdx.x;
  int lane = tid & 63;
  int w = tid >> 6;
  int wm = w >> 1, wn = w & 1;
  int fr = lane & 15, kq = lane >> 4;

  int rowA0 = tid & 127, kb0 = tid >> 7;   // threads cover [kb0(0,1)][row 0..127]
  int gr0 = mt * 128 + rowA0;
  int t0 = (gr0 < ce) ? (list[e * Tt + gr0] >> 1) : 0;
  const unsigned short* a0 = xb + (size_t)t0 * Dd + kb0 * 8;     // +16 elems => kb+2
  const unsigned short* b0 = w1b + (size_t)e * Hh * Dd + (size_t)(nt * 128 + rowA0) * Dd + kb0 * 8;

  short* AdA = &As[w * 512];
  short* AdB = &As[2048 + w * 512];
  short* BdA = &Bs[w * 512];
  short* BdB = &Bs[2048 + w * 512];

  int abase = kq * 1024 + (wm * 64 + fr) * 8;
  int bbase = kq * 1024 + (wn * 64 + fr) * 8;

  // Preload epilogue operands so the in-loop vmcnt counts stay exact.
  const float* b1e = b1 + (size_t)e * Hh;
  float biasj[4];
#pragma unroll
  for (int j = 0; j < 4; j++) biasj[j] = b1e[nt * 128 + wn * 64 + j * 16 + fr];
  asm volatile("s_waitcnt vmcnt(0)" ::: "memory");

  f32x4 acc[4][4] = {};

  STAGE(0, 0);
  STAGE(4096, 32);
  STAGE(8192, 64);

  const int nkt = Dd / 32;  // 32
  int cur = 0;
  for (int kt = 0; kt <= nkt - 4; ++kt) {
    int so = cur * 4096;
    asm volatile("s_waitcnt vmcnt(8)" ::: "memory");
    __builtin_amdgcn_s_barrier();
    COMPUTE(so);
    __builtin_amdgcn_s_barrier();
    STAGE(so, (kt + 3) * 32);
    cur = ROT(cur);
  }
  // drain: tiles nkt-3, nkt-2, nkt-1 in buffers cur, cur+1, cur+2
  asm volatile("s_waitcnt vmcnt(8)" ::: "memory");
  __builtin_amdgcn_s_barrier();
  COMPUTE(cur * 4096);
  cur = ROT(cur);
  asm volatile("s_waitcnt vmcnt(4)" ::: "memory");
  __builtin_amdgcn_s_barrier();
  COMPUTE(cur * 4096);
  cur = ROT(cur);
  asm volatile("s_waitcnt vmcnt(0)" ::: "memory");
  __builtin_amdgcn_s_barrier();
  COMPUTE(cur * 4096);

  int off_e = offs[e];
#pragma unroll
  for (int i = 0; i < 4; i++) {
    int rb = wm * 64 + i * 16 + kq * 4;
#pragma unroll
    for (int j = 0; j < 4; j++) {
      int col = nt * 128 + wn * 64 + j * 16 + fr;
#pragma unroll
      for (int rr = 0; rr < 4; rr++) {
        int grow = mt * 128 + rb + rr;
        if (grow < ce) {
          float v = acc[i][j][rr] + biasj[j];
          v = 0.5f * v * (1.0f + erff(v * 0.70710678118654752f));
          hb[(size_t)(off_e + grow) * Hh + col] = f2bf_bits(v);
        }
      }
    }
  }
}

// ---------------- GEMM2: y = h @ W2[e]^T + b2[e] -> fp32 scattered to (t,k) ----------------
__global__ __launch_bounds__(256) void gemm2_kernel(
    const unsigned short* __restrict__ hb, const unsigned short* __restrict__ w2b,
    const float* __restrict__ b2,
    const int* __restrict__ cnt, const int* __restrict__ offs, const int* __restrict__ list,
    float* __restrict__ y) {
  int bid = blockIdx.x;
  int e = bid & 7;
  int slot = bid >> 3;          // 0..255
  int nt = slot >> 5;           // 0..7   (Dd/128)
  int mt = slot & 31;           // 0..31  (Tt/128), mt-inner
  int ce = cnt[e];
  if (mt * 128 >= ce) return;

  __shared__ short As[3 * 4096];
  __shared__ short Bs[3 * 4096];
  __shared__ int ents[128];

  int tid = threadIdx.x;
  if (tid < 128) {
    int grow = mt * 128 + tid;
    ents[tid] = (grow < ce) ? list[e * Tt + grow] : -1;
  }

  int lane = tid & 63;
  int w = tid >> 6;
  int wm = w >> 1, wn = w & 1;
  int fr = lane & 15, kq = lane >> 4;

  int rowA0 = tid & 127, kb0 = tid >> 7;
  int off_e = offs[e];
  int gA0 = mt * 128 + rowA0; if (gA0 >= ce) gA0 = ce - 1;
  const unsigned short* a0 = hb + (size_t)(off_e + gA0) * Hh + kb0 * 8;
  const unsigned short* b0 = w2b + (size_t)e * Dd * Hh + (size_t)(nt * 128 + rowA0) * Hh + kb0 * 8;

  short* AdA = &As[w * 512];
  short* AdB = &As[2048 + w * 512];
  short* BdA = &Bs[w * 512];
  short* BdB = &Bs[2048 + w * 512];

  int abase = kq * 1024 + (wm * 64 + fr) * 8;
  int bbase = kq * 1024 + (wn * 64 + fr) * 8;

  const float* b2e = b2 + (size_t)e * Dd;
  float biasj[4];
#pragma unroll
  for (int j = 0; j < 4; j++) biasj[j] = b2e[nt * 128 + wn * 64 + j * 16 + fr];
  asm volatile("s_waitcnt vmcnt(0)" ::: "memory");

  f32x4 acc[4][4] = {};

  STAGE(0, 0);
  STAGE(4096, 32);
  STAGE(8192, 64);

  const int nkt = Hh / 32;  // 128
  int cur = 0;
  for (int kt = 0; kt <= nkt - 4; ++kt) {
    int so = cur * 4096;
    asm volatile("s_waitcnt vmcnt(8)" ::: "memory");
    __builtin_amdgcn_s_barrier();
    COMPUTE(so);
    __builtin_amdgcn_s_barrier();
    STAGE(so, (kt + 3) * 32);
    cur = ROT(cur);
  }
  asm volatile("s_waitcnt vmcnt(8)" ::: "memory");
  __builtin_amdgcn_s_barrier();
  COMPUTE(cur * 4096);
  cur = ROT(cur);
  asm volatile("s_waitcnt vmcnt(4)" ::: "memory");
  __builtin_amdgcn_s_barrier();
  COMPUTE(cur * 4096);
  cur = ROT(cur);
  asm volatile("s_waitcnt vmcnt(0)" ::: "memory");
  __builtin_amdgcn_s_barrier();
  COMPUTE(cur * 4096);

#pragma unroll
  for (int i = 0; i < 4; i++) {
    int rb = wm * 64 + i * 16 + kq * 4;
#pragma unroll
    for (int j = 0; j < 4; j++) {
      int col = nt * 128 + wn * 64 + j * 16 + fr;
#pragma unroll
      for (int rr = 0; rr < 4; rr++) {
        int en = ents[rb + rr];
        if (en >= 0) y[(size_t)en * Dd + col] = acc[i][j][rr] + biasj[j];
      }
    }
  }
}

// ---------------- combine: out[t] = g0*y[2t] + g1*y[2t+1] ----------------
__global__ __launch_bounds__(256) void combine_kernel(
    const float* __restrict__ y, const float* __restrict__ g2, float* __restrict__ out) {
  const int C4 = Dd / 4;  // 256
  int i = blockIdx.x * blockDim.x + threadIdx.x;  // over Tt*Dd/4
  int t = i / C4;
  int c = i % C4;
  float g0 = g2[t * 2 + 0];
  float g1 = g2[t * 2 + 1];
  float4 y0 = reinterpret_cast<const float4*>(y)[(size_t)(t * 2 + 0) * C4 + c];
  float4 y1 = reinterpret_cast<const float4*>(y)[(size_t)(t * 2 + 1) * C4 + c];
  float4 o;
  o.x = g0 * y0.x + g1 * y1.x;
  o.y = g0 * y0.y + g1 * y1.y;
  o.z = g0 * y0.z + g1 * y1.z;
  o.w = g0 * y0.w + g1 * y1.w;
  reinterpret_cast<float4*>(out)[i] = o;
}

extern "C" void kernel_launch(void* const* d_in, const int* in_sizes, int n_in,
                              void* d_out, int out_size, void* d_ws, size_t ws_size,
                              hipStream_t stream) {
  const float* x  = (const float*)d_in[0];
  const float* Wr = (const float*)d_in[1];
  const float* br = (const float*)d_in[2];
  const float* W1 = (const float*)d_in[3];
  const float* b1 = (const float*)d_in[4];
  const float* W2 = (const float*)d_in[5];
  const float* b2 = (const float*)d_in[6];
  float* out = (float*)d_out;

  char* base = (char*)d_ws;
  size_t o = 0;
  auto alloc = [&](size_t n) { char* r = base + o; o += (n + 255) & ~(size_t)255; return r; };
  unsigned short* w1b = (unsigned short*)alloc((size_t)Ee * Hh * Dd * 2);
  unsigned short* w2b = (unsigned short*)alloc((size_t)Ee * Dd * Hh * 2);
  unsigned short* xb  = (unsigned short*)alloc((size_t)Tt * Dd * 2);
  unsigned short* hb  = (unsigned short*)alloc((size_t)Tt * Kk * Hh * 2);
  float* y   = (float*)alloc((size_t)Tt * Kk * Dd * 4);
  int* list  = (int*)alloc((size_t)Ee * Tt * 4);
  float* g2  = (float*)alloc((size_t)Tt * Kk * 4);
  int* cnt   = (int*)alloc(Ee * 4);
  int* offs  = (int*)alloc(Ee * 4);
  if (o > ws_size) return;  // workspace too small: fail loudly (output stays poisoned)

  hipMemsetAsync(cnt, 0, Ee * 4, stream);

  cvt_kernel<<<1024, 256, 0, stream>>>(x, xb, Tt * Dd / 4);
  cvt_kernel<<<4096, 256, 0, stream>>>(W1, w1b, Ee * Hh * Dd / 4);
  cvt_kernel<<<4096, 256, 0, stream>>>(W2, w2b, Ee * Dd * Hh / 4);

  router_kernel<<<Tt / 4, 256, 0, stream>>>(x, Wr, br, cnt, list, g2);
  scan_kernel<<<1, 64, 0, stream>>>(cnt, offs);

  gemm1_kernel<<<Ee * (Tt / 128) * (Hh / 128), 256, 0, stream>>>(xb, w1b, b1, cnt, offs, list, hb);
  gemm2_kernel<<<Ee * (Tt / 128) * (Dd / 128), 256, 0, stream>>>(hb, w2b, b2, cnt, offs, list, y);

  combine_kernel<<<(Tt * Dd / 4) / 256, 256, 0, stream>>>(y, g2, out);
}